// Round 4
// baseline (582.275 us; speedup 1.0000x reference)
//
#include <hip/hip_runtime.h>
#include <stdint.h>

#define N_ROWS 65536
#define N_CLS  1000
#define KPAD   1024
#define FEAT   256
#define MT     64          // rows per block (4 waves x 16 rows)
#define BK     64          // k per iteration
#define NIT    (KPAD/BK)   // 16

typedef _Float16 f16x8 __attribute__((ext_vector_type(8)));
typedef _Float16 f16x2 __attribute__((ext_vector_type(2)));
typedef float    f32x4 __attribute__((ext_vector_type(4)));

__device__ __forceinline__ f16x2 as_f16x2(uint32_t u) {
    union { uint32_t u; f16x2 h; } c; c.u = u; return c.h;
}

// Prep: centersT[n][c] = f16(centers[c][n]) zero-padded to KPAD;
// csqh[c] = f16(||centers[c]||^2) zero-padded; zero d_out.
__global__ __launch_bounds__(256) void prep_kernel(const float* __restrict__ centers,
                                                   ushort* __restrict__ centersT,
                                                   ushort* __restrict__ csqh,
                                                   float* __restrict__ out) {
    const int c = blockIdx.x;     // 0..1023
    const int n = threadIdx.x;    // 0..255
    float v = 0.f;
    if (c < N_CLS) v = centers[(size_t)c * FEAT + n];
    union { _Float16 h; ushort s; } cv; cv.h = (_Float16)v;
    centersT[(size_t)n * KPAD + c] = cv.s;
    float sq = v * v;
    #pragma unroll
    for (int off = 32; off > 0; off >>= 1) sq += __shfl_down(sq, off);
    __shared__ float red[4];
    if ((threadIdx.x & 63) == 0) red[threadIdx.x >> 6] = sq;
    __syncthreads();
    if (threadIdx.x == 0) {
        union { _Float16 h; ushort s; } cs;
        cs.h = (_Float16)(red[0] + red[1] + red[2] + red[3]);
        csqh[c] = cs.s;
        if (c == 0) out[0] = 0.f;
    }
}

// Barrier-free K-loop: each wave owns 16 rows x 256 cols. A stages through a
// wave-PRIVATE 2KB LDS buffer (lane-transpose only); same-wave LDS ordering +
// compiler lgkmcnt make it correct with NO s_barrier. B goes global->regs
// (L2-hot 512KB, identical addresses for all waves). A is register-prefetched
// one full iteration ahead; __syncthreads appears only in the epilogue.
__global__ __launch_bounds__(256, 2) void main_kernel(const int* __restrict__ gt,
                                                      const float* __restrict__ features,
                                                      const ushort* __restrict__ centersT,
                                                      const ushort* __restrict__ csqh,
                                                      float* __restrict__ out) {
    __shared__ uint4 As4[4][16 * 8];   // 4 waves x 2KB (16 rows x 8 16B-chunks, XOR-swizzled)
    __shared__ float red[4];

    const int tid  = threadIdx.x;
    const int lane = tid & 63;
    const int w    = tid >> 6;
    const int r    = lane >> 2;      // staging row 0..15 (within wave)
    const int kc   = lane & 3;       // staging k-quarter (16 ints)
    const int ml   = lane & 15;
    const int quad = lane >> 4;
    const int mls  = ml & 7;
    const int mw   = blockIdx.x * MT + w * 16;   // wave's row base

    const int*    gtrow = gt + (size_t)(mw + r) * N_CLS;
    const ushort* cb    = centersT + (size_t)ml * KPAD + quad * 8;  // + nt*16*KPAD + k
    uint4*        AsW   = As4[w];

    f32x4 acc[16];
    #pragma unroll
    for (int i = 0; i < 16; i++)
        #pragma unroll
        for (int k = 0; k < 4; k++) acc[i][k] = 0.f;

    uint32_t rcp = 0;    // packed per-lane count (lo16+hi16), max 128 each
    float    t2  = 0.f;

    // A[0] prefetch (kb = kc*16, +16 <= 64 < N_CLS: always the vector path)
    int4 a0, a1, a2, a3;
    {
        const int4* p = (const int4*)(gtrow + kc * 16);
        a0 = p[0]; a1 = p[1]; a2 = p[2]; a3 = p[3];
    }

    // B group pipeline: 4 groups/iter of 8 frags (ks x nt-half), 2-deep regs
    f16x8 b0[8], b1[8];
    #pragma unroll
    for (int nt = 0; nt < 8; nt++)   // it0 group0: ks=0, nt 0..7
        b0[nt] = *(const f16x8*)(cb + (size_t)(nt * 16) * KPAD);

    for (int it = 0; it < NIT; ++it) {
        const int k0 = it * BK;

        // group1: ks=0, nt 8..15
        #pragma unroll
        for (int nt = 0; nt < 8; nt++)
            b1[nt] = *(const f16x8*)(cb + (size_t)((nt + 8) * 16) * KPAD + k0);

        // csq f16 chunk for this lane's 16 elems (padded to KPAD, in-bounds)
        const int kb = k0 + kc * 16;
        uint4 cq0 = *(const uint4*)(csqh + kb);
        uint4 cq1 = *(const uint4*)(csqh + kb + 8);
        uint32_t cs[8] = {cq0.x, cq0.y, cq0.z, cq0.w, cq1.x, cq1.y, cq1.z, cq1.w};

        // convert A[it] (vmcnt wait on a0..a3 only; issued one iter ago)
        int v[16] = {a0.x, a0.y, a0.z, a0.w, a1.x, a1.y, a1.z, a1.w,
                     a2.x, a2.y, a2.z, a2.w, a3.x, a3.y, a3.z, a3.w};
        uint32_t u[8];
        #pragma unroll
        for (int j = 0; j < 8; j++) {
            uint32_t t = (uint32_t)v[2*j] + ((uint32_t)v[2*j+1] << 16);
            rcp += t;
            u[j] = t * 0x3C00u;            // {0,1} pair -> f16 {0.0,1.0} pair
            t2 = __builtin_amdgcn_fdot2(as_f16x2(u[j]), as_f16x2(cs[j]), t2, false);
        }

        // A[it] -> wave-private LDS (XOR swizzle: chunk c -> c^(r&7))
        AsW[r * 8 + ((2*kc)     ^ (r & 7))] = make_uint4(u[0], u[1], u[2], u[3]);
        AsW[r * 8 + ((2*kc + 1) ^ (r & 7))] = make_uint4(u[4], u[5], u[6], u[7]);

        // A[it+1] prefetch (in flight across 32 MFMAs + next convert)
        if (it + 1 < NIT) {
            const int kb2 = (it + 1) * BK + kc * 16;
            if (kb2 + 16 <= N_CLS) {
                const int4* p = (const int4*)(gtrow + kb2);
                a0 = p[0]; a1 = p[1]; a2 = p[2]; a3 = p[3];
            } else {
                int t16[16];
                #pragma unroll
                for (int j = 0; j < 16; j++) {
                    int k = kb2 + j;
                    t16[j] = (k < N_CLS) ? gtrow[k] : 0;
                }
                a0 = make_int4(t16[0],  t16[1],  t16[2],  t16[3]);
                a1 = make_int4(t16[4],  t16[5],  t16[6],  t16[7]);
                a2 = make_int4(t16[8],  t16[9],  t16[10], t16[11]);
                a3 = make_int4(t16[12], t16[13], t16[14], t16[15]);
            }
        }

        // A fragments (same-wave LDS write->read: in-order pipe + lgkmcnt)
        f16x8 af0 = ((const f16x8*)AsW)[ml * 8 + ( quad      ^ mls)];  // ks=0
        f16x8 af1 = ((const f16x8*)AsW)[ml * 8 + ((4 + quad) ^ mls)];  // ks=1

        // g0 MFMA (ks0, nt0-7), then refill b0 with g2 (ks1, nt0-7)
        #pragma unroll
        for (int nt = 0; nt < 8; nt++)
            acc[nt] = __builtin_amdgcn_mfma_f32_16x16x32_f16(af0, b0[nt], acc[nt], 0, 0, 0);
        #pragma unroll
        for (int nt = 0; nt < 8; nt++)
            b0[nt] = *(const f16x8*)(cb + (size_t)(nt * 16) * KPAD + k0 + 32);

        // g1 MFMA (ks0, nt8-15), then refill b1 with g3 (ks1, nt8-15)
        #pragma unroll
        for (int nt = 0; nt < 8; nt++)
            acc[8+nt] = __builtin_amdgcn_mfma_f32_16x16x32_f16(af0, b1[nt], acc[8+nt], 0, 0, 0);
        #pragma unroll
        for (int nt = 0; nt < 8; nt++)
            b1[nt] = *(const f16x8*)(cb + (size_t)((nt + 8) * 16) * KPAD + k0 + 32);

        // g2 MFMA (ks1, nt0-7), then issue next iter's g0 into b0
        #pragma unroll
        for (int nt = 0; nt < 8; nt++)
            acc[nt] = __builtin_amdgcn_mfma_f32_16x16x32_f16(af1, b0[nt], acc[nt], 0, 0, 0);
        if (it + 1 < NIT) {
            #pragma unroll
            for (int nt = 0; nt < 8; nt++)
                b0[nt] = *(const f16x8*)(cb + (size_t)(nt * 16) * KPAD + k0 + 64);
        }

        // g3 MFMA (ks1, nt8-15)
        #pragma unroll
        for (int nt = 0; nt < 8; nt++)
            acc[8+nt] = __builtin_amdgcn_mfma_f32_16x16x32_f16(af1, b1[nt], acc[8+nt], 0, 0, 0);
    }

    // ---- rowcnt via shuffles (rows are wave-local; lanes 4x..4x+3 hold row x) ----
    float rcf = (float)((rcp & 0xFFFFu) + (rcp >> 16));
    rcf += __shfl_xor(rcf, 1);
    rcf += __shfl_xor(rcf, 2);
    float rw[4];
    #pragma unroll
    for (int reg = 0; reg < 4; reg++)
        rw[reg] = __shfl(rcf, quad * 16 + reg * 4);   // rowcnt[quad*4+reg]

    // ---- epilogue: fold features once; t2 is a per-thread scalar ----
    float part = t2;
    #pragma unroll
    for (int nt = 0; nt < 16; nt++) {
        const int n = nt * 16 + ml;
        #pragma unroll
        for (int reg = 0; reg < 4; reg++) {
            const int ri = quad * 4 + reg;     // row within wave's 16
            const float f = features[(size_t)(mw + ri) * FEAT + n];
            part += f * (rw[reg] * f - 2.f * acc[nt][reg]);
        }
    }
    #pragma unroll
    for (int off = 32; off > 0; off >>= 1) part += __shfl_down(part, off);
    if (lane == 0) red[w] = part;
    __syncthreads();
    if (tid == 0)
        atomicAdd(out, (red[0] + red[1] + red[2] + red[3]) * (1.f / (float)N_ROWS));
}

extern "C" void kernel_launch(void* const* d_in, const int* in_sizes, int n_in,
                              void* d_out, int out_size, void* d_ws, size_t ws_size,
                              hipStream_t stream) {
    const int*   gt       = (const int*)d_in[0];
    const float* features = (const float*)d_in[1];
    const float* centers  = (const float*)d_in[2];
    float*       out      = (float*)d_out;

    ushort* centersT = (ushort*)d_ws;                                    // 512 KB
    ushort* csqh     = (ushort*)((char*)d_ws + (size_t)FEAT * KPAD * 2); // 2 KB

    prep_kernel<<<KPAD, 256, 0, stream>>>(centers, centersT, csqh, out);
    main_kernel<<<N_ROWS / MT, 256, 0, stream>>>(gt, features, centersT, csqh, out);
}

// Round 5
// 446.524 us; speedup vs baseline: 1.3040x; 1.3040x over previous
//
#include <hip/hip_runtime.h>
#include <stdint.h>

#define N_ROWS 65536
#define N_CLS  1000
#define KPAD   1024
#define FEAT   256
#define MT     64
#define NIT    16      // K-loop iters of BK=64
#define PITERS 16      // preamble: 64*1000 / (256*16)

typedef _Float16 f16x8 __attribute__((ext_vector_type(8)));
typedef float    f32x4 __attribute__((ext_vector_type(4)));

// 8 mask bits -> 8 packed f16 {0.0, 1.0}
__device__ __forceinline__ f16x8 expand8(uint32_t b) {
    union { uint32_t u[4]; f16x8 v; } r;
#pragma unroll
    for (int p = 0; p < 4; ++p) {
        uint32_t lo = (b >> (2 * p)) & 1u;
        uint32_t hi = (b >> (2 * p + 1)) & 1u;
        r.u[p] = lo * 0x3C00u + hi * 0x3C000000u;
    }
    return r.v;
}

// Prep: centersT[n][c] = f16(centers[c][n]) zero-padded to KPAD;
// csqf[c] = ||centers[c]||^2 (f32, zero-padded); zero d_out.
__global__ __launch_bounds__(256) void prep_kernel(const float* __restrict__ centers,
                                                   ushort* __restrict__ centersT,
                                                   float* __restrict__ csqf,
                                                   float* __restrict__ out) {
    const int c = blockIdx.x;     // 0..1023
    const int n = threadIdx.x;    // 0..255
    float v = 0.f;
    if (c < N_CLS) v = centers[(size_t)c * FEAT + n];
    union { _Float16 h; ushort s; } cv; cv.h = (_Float16)v;
    centersT[(size_t)n * KPAD + c] = cv.s;
    float sq = v * v;
#pragma unroll
    for (int off = 32; off > 0; off >>= 1) sq += __shfl_down(sq, off);
    __shared__ float red[4];
    if ((threadIdx.x & 63) == 0) red[threadIdx.x >> 6] = sq;
    __syncthreads();
    if (threadIdx.x == 0) {
        csqf[c] = red[0] + red[1] + red[2] + red[3];
        if (c == 0) out[0] = 0.f;
    }
}

// Block = 64 rows x 256 cols. Phase 1: stream the block's CONTIGUOUS 256KB of
// gt (perfect coalescing, no strided lane patterns) into an 8KB LDS bit-panel
// [64][128B], fusing t2. Phase 2: R2-proven barrier GEMM loop; A-frags expand
// from bits (no global A traffic), B staged to LDS from L2-hot centersT.
// LDS = 32K(B) + 8K(panel) = 40960 -> 4 blocks/CU.
__global__ __launch_bounds__(256, 4) void main_kernel(const int* __restrict__ gt,
                                                      const float* __restrict__ features,
                                                      const ushort* __restrict__ centersT,
                                                      const float* __restrict__ csqf,
                                                      float* __restrict__ out) {
    __shared__ uint4 Bs4[FEAT * 8];     // 32 KB B tile
    __shared__ uint4 panelV[512];       //  8 KB bit panel [64 rows][128 B]
    unsigned char* panel = (unsigned char*)panelV;

    const int tid  = threadIdx.x;
    const int m0   = blockIdx.x * MT;
    const int lane = tid & 63;
    const int w    = tid >> 6;
    const int ml   = lane & 15;
    const int quad = lane >> 4;
    const int mls  = ml & 7;

    // zero the panel (padding bytes 125..127 of each row must stay 0)
    panelV[tid]       = make_uint4(0, 0, 0, 0);
    panelV[256 + tid] = make_uint4(0, 0, 0, 0);

    f32x4 acc[4][4];
#pragma unroll
    for (int i = 0; i < 4; i++)
#pragma unroll
        for (int j = 0; j < 4; j++)
#pragma unroll
            for (int k = 0; k < 4; k++) acc[i][j][k] = 0.f;

    float t2 = 0.f;
    const int* gtb = gt + (size_t)m0 * N_CLS;   // block's contiguous 64000 ints

    __syncthreads();

    // ---- Phase 1: contiguous stream -> bit panel + t2 ----
#pragma unroll 1
    for (int p = 0; p < PITERS; ++p) {
        const int o = p * 4096 + tid * 16;      // 16-aligned flat offset
        if (o < MT * N_CLS) {
            const int4* src = (const int4*)(gtb + o);
            int4 q0 = src[0], q1 = src[1], q2 = src[2], q3 = src[3];
            const int vv[16] = {q0.x, q0.y, q0.z, q0.w, q1.x, q1.y, q1.z, q1.w,
                                q2.x, q2.y, q2.z, q2.w, q3.x, q3.y, q3.z, q3.w};
#pragma unroll
            for (int h = 0; h < 2; ++h) {
                const uint32_t ob = (uint32_t)(o + h * 8);
                // floor(ob/1000) for ob<=63992: 67109=(2^26+136)/1000, no u32 ovf
                const uint32_t r = (ob * 67109u) >> 26;
                const uint32_t c = ob - r * 1000u;     // 8-aligned, <=992
                const float4* cp = (const float4*)(csqf + c);
                float4 s0 = cp[0], s1 = cp[1];
                const float cs[8] = {s0.x, s0.y, s0.z, s0.w, s1.x, s1.y, s1.z, s1.w};
                uint32_t m = 0;
#pragma unroll
                for (int j = 0; j < 8; ++j) {
                    const bool bit = vv[h * 8 + j] > 0;
                    m |= (uint32_t)bit << j;
                    t2 += bit ? cs[j] : 0.f;
                }
                panel[r * 128 + (c >> 3)] = (unsigned char)m;
            }
        }
    }

    __syncthreads();   // panel complete

    // ---- Phase 2: K-loop (R2-proven structure) ----
    const uint4* ctv = (const uint4*)centersT;
    for (int it = 0; it < NIT; ++it) {
        if (it) __syncthreads();       // Bs consumed by previous iter
#pragma unroll
        for (int j = 0; j < 8; ++j) {  // stage B slice [n][it*64..+63], 128B segs
            const int g = j * 256 + tid;
            const int n = g >> 3;
            const int kl = g & 7;
            Bs4[n * 8 + (kl ^ (n & 7))] = ctv[n * 128 + it * 8 + kl];
        }
        // A bits for this iter (panel stable -> safe before barrier)
        uint2 bits[4];
#pragma unroll
        for (int mt = 0; mt < 4; ++mt)
            bits[mt] = *(const uint2*)(panel + (mt * 16 + ml) * 128 + it * 8);
        __syncthreads();               // Bs visible
#pragma unroll
        for (int ks = 0; ks < 2; ++ks) {
            f16x8 af[4], bfr[4];
#pragma unroll
            for (int mt = 0; mt < 4; ++mt) {
                const uint32_t by = ((ks ? bits[mt].y : bits[mt].x) >> (8 * quad)) & 0xFFu;
                af[mt] = expand8(by);
            }
            const int lc = ks * 4 + quad;
#pragma unroll
            for (int nt = 0; nt < 4; ++nt)
                bfr[nt] = ((const f16x8*)Bs4)[(w * 64 + nt * 16 + ml) * 8 + (lc ^ mls)];
#pragma unroll
            for (int mt = 0; mt < 4; ++mt)
#pragma unroll
                for (int nt = 0; nt < 4; ++nt)
                    acc[mt][nt] = __builtin_amdgcn_mfma_f32_16x16x32_f16(
                        af[mt], bfr[nt], acc[mt][nt], 0, 0, 0);
        }
    }

    __syncthreads();   // K done; Bs region reusable

    // ---- rowcnt = popcount of panel rows (4 threads/row) ----
    {
        const int row = tid >> 2, part = tid & 3;
        const uint4* rp = (const uint4*)(panel + row * 128 + part * 32);
        uint4 x = rp[0], y = rp[1];
        float cnt = (float)(__popc(x.x) + __popc(x.y) + __popc(x.z) + __popc(x.w) +
                            __popc(y.x) + __popc(y.y) + __popc(y.z) + __popc(y.w));
        cnt += __shfl_xor(cnt, 1);
        cnt += __shfl_xor(cnt, 2);
        if (part == 0) ((float*)Bs4)[row] = cnt;
    }
    __syncthreads();

    // ---- epilogue: fold features once ----
    const float* rowcntL = (const float*)Bs4;
    float ps = t2;
#pragma unroll
    for (int mt = 0; mt < 4; ++mt) {
#pragma unroll
        for (int nt = 0; nt < 4; ++nt) {
            const int n = w * 64 + nt * 16 + ml;
#pragma unroll
            for (int reg = 0; reg < 4; ++reg) {
                const int ri = mt * 16 + quad * 4 + reg;
                const float f = features[(size_t)(m0 + ri) * FEAT + n];
                ps += f * (rowcntL[ri] * f - 2.f * acc[mt][nt][reg]);
            }
        }
    }
#pragma unroll
    for (int off = 32; off > 0; off >>= 1) ps += __shfl_down(ps, off);
    if (lane == 0) ((float*)Bs4)[64 + w] = ps;
    __syncthreads();
    if (tid == 0) {
        const float* S = (const float*)Bs4;
        atomicAdd(out, (S[64] + S[65] + S[66] + S[67]) * (1.f / (float)N_ROWS));
    }
}

extern "C" void kernel_launch(void* const* d_in, const int* in_sizes, int n_in,
                              void* d_out, int out_size, void* d_ws, size_t ws_size,
                              hipStream_t stream) {
    const int*   gt       = (const int*)d_in[0];
    const float* features = (const float*)d_in[1];
    const float* centers  = (const float*)d_in[2];
    float*       out      = (float*)d_out;

    ushort* centersT = (ushort*)d_ws;                                    // 512 KB
    float*  csqf     = (float*)((char*)d_ws + (size_t)FEAT * KPAD * 2);  // 4 KB

    prep_kernel<<<KPAD, 256, 0, stream>>>(centers, centersT, csqf, out);
    main_kernel<<<N_ROWS / MT, 256, 0, stream>>>(gt, features, centersT, csqf, out);
}

// Round 6
// 419.272 us; speedup vs baseline: 1.3888x; 1.0650x over previous
//
#include <hip/hip_runtime.h>
#include <stdint.h>

#define N_ROWS 65536
#define N_CLS  1000
#define FEAT   256
#define MT     64
#define NIT    16       // K-loop iters of BK=64
#define PSTR   136      // panel row stride in bytes (34 dwords -> conflict-free b64)
#define NTILE  17       // 16 feature tiles + 1 (csq | ones) tile

typedef _Float16 f16x8 __attribute__((ext_vector_type(8)));
typedef float    f32x4 __attribute__((ext_vector_type(4)));

__device__ __forceinline__ f16x8 as_f16x8(uint4 u) {
    union { uint4 q; f16x8 v; } c; c.q = u; return c.v;
}

// 8 mask bits -> 8 packed f16 {0.0, 1.0}
__device__ __forceinline__ f16x8 expand8(uint32_t b) {
    union { uint32_t u[4]; f16x8 v; } r;
#pragma unroll
    for (int p = 0; p < 4; ++p) {
        const uint32_t q = (b >> (2 * p)) & 3u;
        r.u[p] = (q & 1u) * 0x3C00u + (q >> 1) * 0x3C000000u;
    }
    return r.v;
}

// K1: csqf[c] = ||centers[c]||^2 (f32, zero-padded to 1024); zero d_out.
__global__ __launch_bounds__(256) void csq_kernel(const float* __restrict__ centers,
                                                  float* __restrict__ csqf,
                                                  float* __restrict__ out) {
    const int c = blockIdx.x;     // 0..1023
    float v = (c < N_CLS) ? centers[(size_t)c * FEAT + threadIdx.x] : 0.f;
    float sq = v * v;
#pragma unroll
    for (int off = 32; off > 0; off >>= 1) sq += __shfl_down(sq, off);
    __shared__ float red[4];
    if ((threadIdx.x & 63) == 0) red[threadIdx.x >> 6] = sq;
    __syncthreads();
    if (threadIdx.x == 0) {
        csqf[c] = red[0] + red[1] + red[2] + red[3];
        if (c == 0) out[0] = 0.f;
    }
}

// K2: pre-swizzle B into MFMA fragment order.
// frag[(nt*32+kk)*64 + lane] = 16B = 8 f16: B[k = kk*32 + (lane>>4)*8 + j][n],
// where B[k][n] = centers[k][nt*16 + (lane&15)] for nt<16;
// tile 16: col0 = csq[k] (f16), col1 = 1.0 (k<1000), else 0.
__global__ __launch_bounds__(64) void frag_kernel(const float* __restrict__ centers,
                                                  const float* __restrict__ csqf,
                                                  uint4* __restrict__ frags) {
    const int nt = blockIdx.x;     // 0..16
    const int kk = blockIdx.y;     // 0..31
    const int l  = threadIdx.x;    // 0..63
    const int ml = l & 15, quad = l >> 4;
    union { _Float16 h[8]; uint4 q; } o;
#pragma unroll
    for (int j = 0; j < 8; ++j) {
        const int k = kk * 32 + quad * 8 + j;
        float v;
        if (nt < 16)      v = (k < N_CLS) ? centers[(size_t)k * FEAT + nt * 16 + ml] : 0.f;
        else if (ml == 0) v = csqf[k];                        // zero-padded
        else if (ml == 1) v = (k < N_CLS) ? 1.f : 0.f;
        else              v = 0.f;
        o.h[j] = (_Float16)v;
    }
    frags[((size_t)nt * 32 + kk) * 64 + l] = o.q;
}

// Main: phase 1 streams the block's contiguous 256KB of gt (dense 64B/lane
// loads) into an 8.5KB LDS bit-panel (stride 136 -> conflict-free reads).
// Phase 2: BARRIER-FREE K-loop; A expands from bits, B via dense dwordx4
// loads of pre-swizzled L2-hot fragments; wave 0 also multiplies the
// (csq|ones) tile so t2row/rowcnt fall out of the MFMA.
__global__ __launch_bounds__(256, 3) void main_kernel(const int* __restrict__ gt,
                                                      const float* __restrict__ features,
                                                      const uint4* __restrict__ frags,
                                                      float* __restrict__ out) {
    __shared__ unsigned char panel[MT * PSTR];   // 8704 B
    __shared__ float t2rc[132];  // [0..63] t2row, [64..127] rowcnt, [128..131] wave partials

    const int tid  = threadIdx.x;
    const int m0   = blockIdx.x * MT;
    const int lane = tid & 63;
    const int w    = tid >> 6;
    const int ml   = lane & 15;
    const int quad = lane >> 4;

    // ---- Phase 1: contiguous gt stream -> bit panel ----
    const int* gtb = gt + (size_t)m0 * N_CLS;
#pragma unroll 1
    for (int p = 0; p < 16; ++p) {
        const int o = p * 4096 + tid * 16;
        if (o < MT * N_CLS) {
            const int4* src = (const int4*)(gtb + o);
            int4 q0 = src[0], q1 = src[1], q2 = src[2], q3 = src[3];
            const int vv[16] = {q0.x, q0.y, q0.z, q0.w, q1.x, q1.y, q1.z, q1.w,
                                q2.x, q2.y, q2.z, q2.w, q3.x, q3.y, q3.z, q3.w};
#pragma unroll
            for (int h = 0; h < 2; ++h) {
                const uint32_t ob = (uint32_t)(o + h * 8);
                const uint32_t r  = (ob * 67109u) >> 26;   // exact /1000 for 8-aligned ob<=63992
                const uint32_t c  = ob - r * 1000u;
                uint32_t m = 0;
#pragma unroll
                for (int j = 0; j < 8; ++j) m |= (uint32_t)(vv[h * 8 + j] & 1) << j;
                panel[r * PSTR + (c >> 3)] = (unsigned char)m;
            }
        }
    }
    __syncthreads();   // panel complete; the ONLY barrier before the epilogue

    // ---- Phase 2: barrier-free K-loop ----
    f32x4 acc[4][4], acce[4];
#pragma unroll
    for (int i = 0; i < 4; i++) {
#pragma unroll
        for (int j = 0; j < 4; j++)
#pragma unroll
            for (int k = 0; k < 4; k++) acc[i][j][k] = 0.f;
#pragma unroll
        for (int k = 0; k < 4; k++) acce[i][k] = 0.f;
    }

    for (int it = 0; it < NIT; ++it) {
        // A bits: 4 conflict-free ds_read_b64 (rows mt*16+ml, bytes it*8..+7)
        uint2 bits[4];
#pragma unroll
        for (int mt = 0; mt < 4; ++mt)
            bits[mt] = *(const uint2*)(panel + (mt * 16 + ml) * PSTR + it * 8);

        // B frags: dense dwordx4, L2-hot
        uint4 bf[2][4], ebf[2];
#pragma unroll
        for (int ks = 0; ks < 2; ++ks)
#pragma unroll
            for (int nt = 0; nt < 4; ++nt)
                bf[ks][nt] = frags[(size_t)(((w * 4 + nt) * 32) + it * 2 + ks) * 64 + lane];
        if (w == 0) {
#pragma unroll
            for (int ks = 0; ks < 2; ++ks)
                ebf[ks] = frags[(size_t)((16 * 32) + it * 2 + ks) * 64 + lane];
        }

#pragma unroll
        for (int ks = 0; ks < 2; ++ks) {
            f16x8 af[4];
#pragma unroll
            for (int mt = 0; mt < 4; ++mt) {
                const uint32_t by = ((ks ? bits[mt].y : bits[mt].x) >> (8 * quad)) & 0xFFu;
                af[mt] = expand8(by);
            }
#pragma unroll
            for (int mt = 0; mt < 4; ++mt)
#pragma unroll
                for (int nt = 0; nt < 4; ++nt)
                    acc[mt][nt] = __builtin_amdgcn_mfma_f32_16x16x32_f16(
                        af[mt], as_f16x8(bf[ks][nt]), acc[mt][nt], 0, 0, 0);
            if (w == 0) {
#pragma unroll
                for (int mt = 0; mt < 4; ++mt)
                    acce[mt] = __builtin_amdgcn_mfma_f32_16x16x32_f16(
                        af[mt], as_f16x8(ebf[ks]), acce[mt], 0, 0, 0);
            }
        }
    }

    __syncthreads();   // all waves done with panel / K-loop
    if (w == 0 && ml < 2) {
        // C/D layout: col=lane&15, row=quad*4+reg. col0 = t2row, col1 = rowcnt.
#pragma unroll
        for (int mt = 0; mt < 4; ++mt)
#pragma unroll
            for (int reg = 0; reg < 4; ++reg)
                t2rc[ml * 64 + mt * 16 + quad * 4 + reg] = acce[mt][reg];
    }
    __syncthreads();

    // ---- epilogue: fold features once ----
    float ps = 0.f;
#pragma unroll
    for (int mt = 0; mt < 4; ++mt) {
#pragma unroll
        for (int nt = 0; nt < 4; ++nt) {
            const int n = w * 64 + nt * 16 + ml;
#pragma unroll
            for (int reg = 0; reg < 4; ++reg) {
                const int ri = mt * 16 + quad * 4 + reg;
                const float f = features[(size_t)(m0 + ri) * FEAT + n];
                ps += f * (t2rc[64 + ri] * f - 2.f * acc[mt][nt][reg])
                      + t2rc[ri] * (1.f / 256.f);
            }
        }
    }
#pragma unroll
    for (int off = 32; off > 0; off >>= 1) ps += __shfl_down(ps, off);
    if (lane == 0) t2rc[128 + w] = ps;
    __syncthreads();
    if (tid == 0)
        atomicAdd(out, (t2rc[128] + t2rc[129] + t2rc[130] + t2rc[131]) *
                           (1.f / (float)N_ROWS));
}

extern "C" void kernel_launch(void* const* d_in, const int* in_sizes, int n_in,
                              void* d_out, int out_size, void* d_ws, size_t ws_size,
                              hipStream_t stream) {
    const int*   gt       = (const int*)d_in[0];
    const float* features = (const float*)d_in[1];
    const float* centers  = (const float*)d_in[2];
    float*       out      = (float*)d_out;

    uint4* frags = (uint4*)d_ws;                                     // 17*32*64*16 = 544 KB
    float* csqf  = (float*)((char*)d_ws + (size_t)NTILE * 32 * 64 * 16);  // 4 KB

    csq_kernel<<<1024, 256, 0, stream>>>(centers, csqf, out);
    frag_kernel<<<dim3(NTILE, 32), 64, 0, stream>>>(centers, csqf, frags);
    main_kernel<<<N_ROWS / MT, 256, 0, stream>>>(gt, features, frags, out);
}